// Round 7
// baseline (484.819 us; speedup 1.0000x reference)
//
#include <hip/hip_runtime.h>
#include <hip/hip_bf16.h>
#include <math.h>

// Problem constants
#define BB 4
#define NN 1024
#define DD 256
#define CC 8
#define KNBR 16
#define MAXSEL 17   // 16 top-k + possibly the diagonal
#define ZCAP (NN * MAXSEL)   // 17408 max CSR entries per z

typedef __bf16 bf16x8_t __attribute__((ext_vector_type(8)));
typedef float  f32x4_t  __attribute__((ext_vector_type(4)));

// async global->LDS, 16 bytes per lane. LDS base wave-uniform; source address
// is per-lane (gather allowed, keep it coalesced).
__device__ __forceinline__ void gl2lds16(const __bf16* g, __bf16* ldsbase) {
    __builtin_amdgcn_global_load_lds(
        (const __attribute__((address_space(1))) unsigned int*)g,
        (__attribute__((address_space(3))) unsigned int*)ldsbase, 16, 0, 0);
}

// 3-level bf16 split: v = h + m + l + eps, |eps| <= 2^-24 |v|
__device__ __forceinline__ void split3(float v, __bf16& h, __bf16& m, __bf16& l) {
    h = (__bf16)v;
    float r = v - (float)h;
    m = (__bf16)r;
    l = (__bf16)(r - (float)m);
}

// ---------------------------------------------------------------------------
// Kernel 0: fused input prep. Blocks 0..1023: split x. Blocks 1024..1279:
// transpose+split W. Block 1024 zeroes countb; block 1025 zeroes colsum.
// ---------------------------------------------------------------------------
__global__ __launch_bounds__(256) void split_all(const float* __restrict__ x,
                                                 const float* __restrict__ W,
                                                 __bf16* __restrict__ xh,
                                                 __bf16* __restrict__ xm,
                                                 __bf16* __restrict__ xl,
                                                 __bf16* __restrict__ Wth,
                                                 __bf16* __restrict__ Wtm,
                                                 __bf16* __restrict__ Wtl,
                                                 int* __restrict__ countb,
                                                 float* __restrict__ colsum) {
    const int tid = threadIdx.x;
    if (blockIdx.x < 1024) {
        int i = (blockIdx.x * 256 + tid) * 4;
        float4 v = *(const float4*)(x + i);
        __bf16 h0, m0, l0, h1, m1, l1, h2, m2, l2, h3, m3, l3;
        split3(v.x, h0, m0, l0);
        split3(v.y, h1, m1, l1);
        split3(v.z, h2, m2, l2);
        split3(v.w, h3, m3, l3);
        xh[i] = h0; xh[i + 1] = h1; xh[i + 2] = h2; xh[i + 3] = h3;
        xm[i] = m0; xm[i + 1] = m1; xm[i + 2] = m2; xm[i + 3] = m3;
        xl[i] = l0; xl[i + 1] = l1; xl[i + 2] = l2; xl[i + 3] = l3;
    } else {
        const int b2 = blockIdx.x - 1024;
        if (b2 == 0) {
            int4 zz = make_int4(0, 0, 0, 0);
#pragma unroll
            for (int g = 0; g < 4; g++) ((int4*)countb)[tid + 256 * g] = zz;
        }
        if (b2 == 1) {
            float4 zz = make_float4(0.f, 0.f, 0.f, 0.f);
#pragma unroll
            for (int g = 0; g < 32; g++) ((float4*)colsum)[tid + 256 * g] = zz;
        }
        __shared__ float t[64][65];
        const int n0 = (b2 & 63) * 64;
        const int k0 = (b2 >> 6) * 64;
#pragma unroll
        for (int i = 0; i < 16; i++) {
            int k = i * 4 + (tid >> 6);
            int n = tid & 63;
            t[k][n] = W[(size_t)(k0 + k) * 4096 + n0 + n];
        }
        __syncthreads();
#pragma unroll
        for (int i = 0; i < 16; i++) {
            int n = i * 4 + (tid >> 6);
            int k = tid & 63;
            __bf16 h, m, l;
            split3(t[k][n], h, m, l);
            size_t o = (size_t)(n0 + n) * 256 + k0 + k;
            Wth[o] = h; Wtm[o] = m; Wtl[o] = l;
        }
    }
}

// stage one 128x32 bf16 tile. XOR-swizzled: LDS[r][c] = global[r][c ^ s(r)],
// s(r) = (r&3)^((r>>2)&3). Source stays 64B-coalesced (chunks permuted within
// one row's 64B line).
#define STAGE1(dst, src, rowbase)                                              \
    do {                                                                       \
        gl2lds16(src + (size_t)((rowbase) + r_st) * 256 + k0 + c8s,            \
                 &dst[(w * 64) * 8]);                                          \
        gl2lds16(src + (size_t)((rowbase) + 64 + r_st) * 256 + k0 + c8s,       \
                 &dst[(256 + w * 64) * 8]);                                    \
    } while (0)

// 6-term product ladder, smallest first (hh last)
#define MFMA6(accv, AH, AM, AL, BH, BM, BL)                                    \
    do {                                                                       \
        accv = __builtin_amdgcn_mfma_f32_16x16x32_bf16(AL, BH, accv, 0, 0, 0); \
        accv = __builtin_amdgcn_mfma_f32_16x16x32_bf16(AH, BL, accv, 0, 0, 0); \
        accv = __builtin_amdgcn_mfma_f32_16x16x32_bf16(AM, BM, accv, 0, 0, 0); \
        accv = __builtin_amdgcn_mfma_f32_16x16x32_bf16(AM, BH, accv, 0, 0, 0); \
        accv = __builtin_amdgcn_mfma_f32_16x16x32_bf16(AH, BM, accv, 0, 0, 0); \
        accv = __builtin_amdgcn_mfma_f32_16x16x32_bf16(AH, BH, accv, 0, 0, 0); \
    } while (0)

// ---------------------------------------------------------------------------
// Kernel 1: qk = x @ W via 6-term bf16x3 MFMA; swizzled LDS; LDS-transpose
// epilogue with coalesced bf16x8 stores of the 3-split q/k components.
// ---------------------------------------------------------------------------
__global__ __launch_bounds__(256) void gemm_xw_mfma(
        const __bf16* __restrict__ xh, const __bf16* __restrict__ xm,
        const __bf16* __restrict__ xl, const __bf16* __restrict__ wth,
        const __bf16* __restrict__ wtm, const __bf16* __restrict__ wtl,
        __bf16* __restrict__ qh, __bf16* __restrict__ qm, __bf16* __restrict__ ql,
        __bf16* __restrict__ kh, __bf16* __restrict__ km, __bf16* __restrict__ kl) {
    __shared__ __align__(16) char smem[49152];
    __bf16* Ah = (__bf16*)smem;
    __bf16* Am = Ah + 4096;
    __bf16* Al = Am + 4096;
    __bf16* Bh = Al + 4096;
    __bf16* Bm = Bh + 4096;
    __bf16* Bl = Bm + 4096;
    const int tid = threadIdx.x, lane = tid & 63, w = tid >> 6;
    const int wr = w >> 1, wc = w & 1;
    const int lm = lane & 15, quad = lane >> 4;
    const int row0 = blockIdx.y * 128, col0 = blockIdx.x * 128;
    const int r_st = tid >> 2;
    const int c8s = (((tid & 3) ^ ((tid >> 2) & 3) ^ ((tid >> 4) & 3))) * 8;
    const int rsw = (lm & 3) ^ ((lm >> 2) & 3);   // read-side swizzle (row = base16+lm)
    const int qsw = (quad ^ rsw) * 8;

    f32x4_t acc[4][4];
#pragma unroll
    for (int i = 0; i < 4; i++)
#pragma unroll
        for (int j = 0; j < 4; j++) acc[i][j] = (f32x4_t)(0.f);

    for (int k0 = 0; k0 < 256; k0 += 32) {
        __syncthreads();
        STAGE1(Ah, xh, row0); STAGE1(Am, xm, row0); STAGE1(Al, xl, row0);
        STAGE1(Bh, wth, col0); STAGE1(Bm, wtm, col0); STAGE1(Bl, wtl, col0);
        __syncthreads();

        bf16x8_t ah[4], am[4], al[4];
#pragma unroll
        for (int mi = 0; mi < 4; mi++) {
            int r = (wr * 64 + mi * 16 + lm) * 32 + qsw;
            ah[mi] = *(const bf16x8_t*)&Ah[r];
            am[mi] = *(const bf16x8_t*)&Am[r];
            al[mi] = *(const bf16x8_t*)&Al[r];
        }
#pragma unroll
        for (int ni = 0; ni < 4; ni++) {
            int rb = (wc * 64 + ni * 16 + lm) * 32 + qsw;
            bf16x8_t bh = *(const bf16x8_t*)&Bh[rb];
            bf16x8_t bm = *(const bf16x8_t*)&Bm[rb];
            bf16x8_t bl = *(const bf16x8_t*)&Bl[rb];
#pragma unroll
            for (int mi = 0; mi < 4; mi++)
                MFMA6(acc[mi][ni], ah[mi], am[mi], al[mi], bh, bm, bl);
        }
    }

    // Epilogue: two 64-row passes through LDS (fp32, stride 132 = bank-safe),
    // then coalesced bf16x8 stores of the 3 split components.
    __syncthreads();
    float* tr = (float*)smem;   // 64 x 132 fp32 = 33792 B
    const int s = col0 >> 11, c = (col0 >> 8) & 7, dbase = col0 & 255;
    __bf16* dh = s ? kh : qh;
    __bf16* dm = s ? km : qm;
    __bf16* dl = s ? kl : ql;
    const int rl = tid >> 2;
    const int cb = (tid & 3) * 8;
#pragma unroll
    for (int p = 0; p < 2; p++) {
        if (p) __syncthreads();
        if (wr == p) {
#pragma unroll
            for (int mi = 0; mi < 4; mi++) {
                int rloc = mi * 16 + quad * 4;
#pragma unroll
                for (int ni = 0; ni < 4; ni++) {
                    int cl = wc * 64 + ni * 16 + lm;
#pragma unroll
                    for (int r = 0; r < 4; r++)
                        tr[(rloc + r) * 132 + cl] = acc[mi][ni][r];
                }
            }
        }
        __syncthreads();
        int rr = row0 + p * 64 + rl;
        int bb = rr >> 10, n = rr & 1023;
        size_t base = (((size_t)(bb * CC + c)) * NN + n) * DD + dbase;
#pragma unroll
        for (int g = 0; g < 4; g++) {
            int ccol = g * 32 + cb;
            bf16x8_t hv, mv, lv;
#pragma unroll
            for (int e = 0; e < 8; e++) {
                float vv = tr[rl * 132 + ccol + e];
                __bf16 h, m, l;
                split3(vv, h, m, l);
                hv[e] = h; mv[e] = m; lv[e] = l;
            }
            *(bf16x8_t*)(dh + base + ccol) = hv;
            *(bf16x8_t*)(dm + base + ccol) = mv;
            *(bf16x8_t*)(dl + base + ccol) = lv;
        }
    }
}

// ---------------------------------------------------------------------------
// Kernel 2: per z: attn = (q @ k^T) * scale via 6-term bf16x3 MFMA.
// 1D grid of 2048, swizzled so all 64 blocks of a z share one XCD (id%8);
// XOR-swizzled LDS for conflict-free ds_read_b128.
// ---------------------------------------------------------------------------
__global__ __launch_bounds__(256) void gemm_qkt_mfma(
        const __bf16* __restrict__ qh, const __bf16* __restrict__ qm,
        const __bf16* __restrict__ ql, const __bf16* __restrict__ kh,
        const __bf16* __restrict__ km, const __bf16* __restrict__ kl,
        float* __restrict__ attn) {
    __shared__ __bf16 Ah[128 * 32], Am[128 * 32], Al[128 * 32];
    __shared__ __bf16 Bh[128 * 32], Bm[128 * 32], Bl[128 * 32];
    const int tid = threadIdx.x, lane = tid & 63, w = tid >> 6;
    const int wr = w >> 1, wc = w & 1;
    const int lm = lane & 15, quad = lane >> 4;
    const int id = blockIdx.x;
    const int rb8 = id & 7, qq = id >> 3;
    const int j = qq & 63, zhi = qq >> 6;
    const int z = zhi * 8 + rb8;
    const int row0 = (j >> 3) * 128, col0 = (j & 7) * 128;
    const size_t zo = (size_t)z * NN * DD;
    float* Cm = attn + (size_t)z * NN * NN;
    const int r_st = tid >> 2;
    const int c8s = (((tid & 3) ^ ((tid >> 2) & 3) ^ ((tid >> 4) & 3))) * 8;
    const int rsw = (lm & 3) ^ ((lm >> 2) & 3);
    const int qsw = (quad ^ rsw) * 8;
    const float scale = 0.0625f;

    f32x4_t acc[4][4];
#pragma unroll
    for (int i = 0; i < 4; i++)
#pragma unroll
        for (int j2 = 0; j2 < 4; j2++) acc[i][j2] = (f32x4_t)(0.f);

    for (int k0 = 0; k0 < 256; k0 += 32) {
        __syncthreads();
        STAGE1(Ah, (qh + zo), row0); STAGE1(Am, (qm + zo), row0); STAGE1(Al, (ql + zo), row0);
        STAGE1(Bh, (kh + zo), col0); STAGE1(Bm, (km + zo), col0); STAGE1(Bl, (kl + zo), col0);
        __syncthreads();

        bf16x8_t ah[4], am[4], al[4];
#pragma unroll
        for (int mi = 0; mi < 4; mi++) {
            int r = (wr * 64 + mi * 16 + lm) * 32 + qsw;
            ah[mi] = *(const bf16x8_t*)&Ah[r];
            am[mi] = *(const bf16x8_t*)&Am[r];
            al[mi] = *(const bf16x8_t*)&Al[r];
        }
#pragma unroll
        for (int ni = 0; ni < 4; ni++) {
            int rbb = (wc * 64 + ni * 16 + lm) * 32 + qsw;
            bf16x8_t bh = *(const bf16x8_t*)&Bh[rbb];
            bf16x8_t bm = *(const bf16x8_t*)&Bm[rbb];
            bf16x8_t bl = *(const bf16x8_t*)&Bl[rbb];
#pragma unroll
            for (int mi = 0; mi < 4; mi++)
                MFMA6(acc[mi][ni], ah[mi], am[mi], al[mi], bh, bm, bl);
        }
    }

#pragma unroll
    for (int mi = 0; mi < 4; mi++)
#pragma unroll
        for (int ni = 0; ni < 4; ni++) {
            int row = row0 + wr * 64 + mi * 16 + quad * 4;
            int col = col0 + wc * 64 + ni * 16 + lm;
#pragma unroll
            for (int r = 0; r < 4; r++)
                Cm[(size_t)(row + r) * NN + col] = acc[mi][ni][r] * scale;
        }
}

// ---------------------------------------------------------------------------
// Kernel 3: per (b,n): softmax for all 8 channels (wave w owns channels
// 2w,2w+1; probs stashed in LDS), column channel-sum, wave-parallel top-16,
// 64-candidate merge, then fused rownorm: nr + colsum atomics. ~4 barriers.
// ---------------------------------------------------------------------------
__global__ __launch_bounds__(256) void softmax_topk(const float* __restrict__ attn,
                                                    int* __restrict__ idx,
                                                    int* __restrict__ cnt,
                                                    int* __restrict__ countb,
                                                    float* __restrict__ nr,
                                                    float* __restrict__ colsum) {
    __shared__ float prob[CC][NN];   // 32 KB
    __shared__ float cval[64];
    __shared__ int cidx[64];
    __shared__ int fsel[MAXSEL];
    __shared__ int fcnt;
    const int bn = blockIdx.x, b = bn >> 10, n = bn & 1023;
    const int tid = threadIdx.x, lane = tid & 63, w = tid >> 6;

    // 1) per-wave softmax of channels 2w, 2w+1; stash probs
#pragma unroll
    for (int cc = 0; cc < 2; cc++) {
        const int c = w * 2 + cc;
        const float* src = attn + ((size_t)(b * CC + c) * NN + n) * NN;
        float4 v[4];
#pragma unroll
        for (int g = 0; g < 4; g++) v[g] = *(const float4*)(src + g * 256 + lane * 4);
        float mx = -INFINITY;
#pragma unroll
        for (int g = 0; g < 4; g++)
            mx = fmaxf(mx, fmaxf(fmaxf(v[g].x, v[g].y), fmaxf(v[g].z, v[g].w)));
#pragma unroll
        for (int off = 32; off; off >>= 1) mx = fmaxf(mx, __shfl_xor(mx, off));
        float sm = 0.f;
#pragma unroll
        for (int g = 0; g < 4; g++) {
            v[g].x = expf(v[g].x - mx); v[g].y = expf(v[g].y - mx);
            v[g].z = expf(v[g].z - mx); v[g].w = expf(v[g].w - mx);
            sm += v[g].x + v[g].y + v[g].z + v[g].w;
        }
#pragma unroll
        for (int off = 32; off; off >>= 1) sm += __shfl_xor(sm, off);
        const float inv = 1.0f / sm;
#pragma unroll
        for (int g = 0; g < 4; g++) {
            v[g].x *= inv; v[g].y *= inv; v[g].z *= inv; v[g].w *= inv;
            *(float4*)&prob[c][g * 256 + lane * 4] = v[g];
        }
    }
    __syncthreads();

    // 2) channel-sum for this thread's 4 columns (cols tid*4..tid*4+3)
    float va[4];
    {
        float4 a4 = make_float4(0.f, 0.f, 0.f, 0.f);
#pragma unroll
        for (int c = 0; c < CC; c++) {
            float4 p = *(const float4*)&prob[c][tid * 4];
            a4.x += p.x; a4.y += p.y; a4.z += p.z; a4.w += p.w;
        }
        va[0] = a4.x; va[1] = a4.y; va[2] = a4.z; va[3] = a4.w;
    }

    // 3) per-wave top-16 over cols [w*256, w*256+256), register-resident
    float keepv = -INFINITY; int keepi = 0;
    for (int it = 0; it < KNBR; it++) {
        float bv = va[0]; int bj = 0;
#pragma unroll
        for (int j = 1; j < 4; j++)
            if (va[j] > bv) { bv = va[j]; bj = j; }
        int bi = tid * 4 + bj;
#pragma unroll
        for (int off = 1; off < 64; off <<= 1) {
            float ov = __shfl_xor(bv, off);
            int oi = __shfl_xor(bi, off);
            if (ov > bv || (ov == bv && oi < bi)) { bv = ov; bi = oi; }
        }
        if (lane == it) { keepv = bv; keepi = bi; }
        if ((bi >> 2) == tid) va[bi & 3] = -INFINITY;
    }
    if (lane < KNBR) { cval[w * KNBR + lane] = keepv; cidx[w * KNBR + lane] = keepi; }
    __syncthreads();

    // 4) wave 0 merges the 64 candidates (indices globally unique)
    if (w == 0) {
        float curv = cval[lane]; int curi = cidx[lane];
        int gsel = 0;
        for (int it = 0; it < KNBR; it++) {
            float bv = curv; int bi = curi;
#pragma unroll
            for (int off = 1; off < 64; off <<= 1) {
                float ov = __shfl_xor(bv, off);
                int oi = __shfl_xor(bi, off);
                if (ov > bv || (ov == bv && oi < bi)) { bv = ov; bi = oi; }
            }
            if (lane == it) gsel = bi;
            if (curi == bi) curv = -INFINITY;
        }
        if (lane < KNBR) fsel[lane] = gsel;
    }
    __syncthreads();
    if (tid == 0) {
        bool has = false;
        for (int t = 0; t < KNBR; t++)
            if (fsel[t] == n) has = true;
        int c = KNBR;
        if (!has) { fsel[KNBR] = n; c = KNBR + 1; }
        fcnt = c;
        cnt[bn] = c;
    }
    __syncthreads();
    const int c_ = fcnt;
    if (tid < c_) {
        idx[bn * MAXSEL + tid] = fsel[tid];
        atomicAdd(&countb[b * NN + fsel[tid]], 1);
    }

    // 5) fused rownorm: wave w normalizes its 2 channels' selected probs
#pragma unroll
    for (int cc = 0; cc < 2; cc++) {
        const int c = w * 2 + cc;
        const int z = b * CC + c;
        const int t = z * NN + n;
        float p = (lane < c_) ? prob[c][fsel[lane]] : 0.f;
        float s = p;
#pragma unroll
        for (int off = 1; off < 64; off <<= 1) s += __shfl_xor(s, off);
        float v = p / (s + 1e-6f);
        if (lane < c_) {
            nr[(size_t)t * MAXSEL + lane] = v;
            atomicAdd(&colsum[(size_t)z * NN + fsel[lane]], v);
        }
    }
}

// ---------------------------------------------------------------------------
// Kernel 4: per b: exclusive prefix scan of countb -> offb; init curs.
// ---------------------------------------------------------------------------
__global__ __launch_bounds__(256) void scan_offb(const int* __restrict__ countb,
                                                 int* __restrict__ offb,
                                                 int* __restrict__ curs) {
    __shared__ int wtot[4];
    const int b = blockIdx.x, tid = threadIdx.x, lane = tid & 63, w = tid >> 6;
    int c0 = countb[b * NN + tid * 4 + 0];
    int c1 = countb[b * NN + tid * 4 + 1];
    int c2 = countb[b * NN + tid * 4 + 2];
    int c3 = countb[b * NN + tid * 4 + 3];
    int tsum = c0 + c1 + c2 + c3;
    int incl = tsum;
#pragma unroll
    for (int off = 1; off < 64; off <<= 1) {
        int v = __shfl_up(incl, off);
        if (lane >= off) incl += v;
    }
    if (lane == 63) wtot[w] = incl;
    __syncthreads();
    int woff = 0;
    for (int i = 0; i < w; i++) woff += wtot[i];
    int base = woff + incl - tsum;
    int o0 = base, o1 = base + c0, o2 = base + c0 + c1, o3 = base + c0 + c1 + c2;
    offb[b * NN + tid * 4 + 0] = o0;
    offb[b * NN + tid * 4 + 1] = o1;
    offb[b * NN + tid * 4 + 2] = o2;
    offb[b * NN + tid * 4 + 3] = o3;
#pragma unroll
    for (int c = 0; c < CC; c++) {
        int z = b * CC + c;
        curs[z * NN + tid * 4 + 0] = o0;
        curs[z * NN + tid * 4 + 1] = o1;
        curs[z * NN + tid * 4 + 2] = o2;
        curs[z * NN + tid * 4 + 3] = o3;
    }
}

// ---------------------------------------------------------------------------
// Kernel 5: fill CSR entries from nr/idx (tiny: 2.5 MB traffic).
// ---------------------------------------------------------------------------
__global__ __launch_bounds__(256) void fill_csr(const float* __restrict__ nr,
                                                const int* __restrict__ idx,
                                                const int* __restrict__ cnt,
                                                int* __restrict__ curs,
                                                int* __restrict__ eidx,
                                                float* __restrict__ eval) {
    const int t = blockIdx.x * 256 + threadIdx.x;  // z*N + n
    const int z = t >> 10, n = t & 1023;
    const int b = z >> 3;
    const int bn = b * NN + n;
    const int c_ = cnt[bn];
    const size_t zb = (size_t)z * ZCAP;
#pragma unroll
    for (int j = 0; j < MAXSEL; j++) {
        if (j < c_) {
            int k = idx[bn * MAXSEL + j];
            float v = nr[(size_t)t * MAXSEL + j];
            int p = atomicAdd(&curs[z * NN + k], 1);
            eidx[zb + p] = n;
            eval[zb + p] = v;
        }
    }
}

// ---------------------------------------------------------------------------
// Kernel 6: out[z][n][:] = sum_j w_j/(colsum_j+eps) * sparse_col(k_j).
// Block per (z,n). 17 groups of 15 threads, contiguous CSR slices.
// ---------------------------------------------------------------------------
__global__ __launch_bounds__(256) void out_sparse(const float* __restrict__ nr,
                                                  const int* __restrict__ idx,
                                                  const int* __restrict__ cnt,
                                                  const int* __restrict__ offb,
                                                  const int* __restrict__ countb,
                                                  const float* __restrict__ colsum,
                                                  const int* __restrict__ eidx,
                                                  const float* __restrict__ eval,
                                                  float* __restrict__ out) {
    __shared__ float row[NN];
    __shared__ float gscale[MAXSEL];
    __shared__ int goff[MAXSEL];
    __shared__ int glen[MAXSEL];
    const int t = blockIdx.x;  // z*N + n
    const int z = t >> 10;
    const int b = z >> 3;
    const int bn = b * NN + (t & 1023);
    const int tid = threadIdx.x;
    const size_t zb = (size_t)z * ZCAP;

    ((float4*)row)[tid] = make_float4(0.f, 0.f, 0.f, 0.f);
    const int c_ = cnt[bn];
    if (tid < MAXSEL) {
        float sc = 0.f;
        int off = 0, len = 0;
        if (tid < c_) {
            int k = idx[bn * MAXSEL + tid];
            float wgt = nr[(size_t)t * MAXSEL + tid];
            sc = wgt / (colsum[(size_t)z * NN + k] + 1e-6f);
            off = offb[b * NN + k];
            len = countb[b * NN + k];
        }
        gscale[tid] = sc; goff[tid] = off; glen[tid] = len;
    }
    __syncthreads();
    const int j = tid / 15;       // 17 groups of 15 (tid 255 idle)
    const int lg = tid - j * 15;
    if (j < MAXSEL) {
        const float sc = gscale[j];
        const int off = goff[j], len = glen[j];
        for (int i = lg; i < len; i += 15) {
            int m = eidx[zb + off + i];
            float v = eval[zb + off + i];
            atomicAdd(&row[m], sc * v);
        }
    }
    __syncthreads();
    *(float4*)(out + (size_t)t * NN + tid * 4) = ((float4*)row)[tid];
}

// ---------------------------------------------------------------------------
extern "C" void kernel_launch(void* const* d_in, const int* in_sizes, int n_in,
                              void* d_out, int out_size, void* d_ws, size_t ws_size,
                              hipStream_t stream) {
    const float* x = (const float*)d_in[0];    // [4,1024,256]
    const float* W = (const float*)d_in[1];    // [256,4096]
    float* out = (float*)d_out;                // [4,8,1024,1024]
    char* ws = (char*)d_ws;

    // attn (raw logits*scale) lives in d_out; dead before out_sparse writes.
    float* attn = (float*)d_out;

    // workspace layout (bytes)
    __bf16* qh   = (__bf16*)(ws);
    __bf16* qm   = (__bf16*)(ws + 16777216ull);
    __bf16* ql   = (__bf16*)(ws + 33554432ull);
    __bf16* kh   = (__bf16*)(ws + 50331648ull);
    __bf16* km   = (__bf16*)(ws + 67108864ull);
    __bf16* kl   = (__bf16*)(ws + 83886080ull);
    __bf16* xh   = (__bf16*)(ws + 100663296ull);
    __bf16* xm   = (__bf16*)(ws + 102760448ull);
    __bf16* xl   = (__bf16*)(ws + 104857600ull);
    __bf16* wth  = (__bf16*)(ws + 106954752ull);
    __bf16* wtm  = (__bf16*)(ws + 109051904ull);
    __bf16* wtl  = (__bf16*)(ws + 111149056ull);
    int*    idx  = (int*)   (ws + 113246208ull);   // 278,528
    int*    cnt  = (int*)   (ws + 113524736ull);   // 16,384
    float*  nr   = (float*) (ws + 113541120ull);   // 2,228,224
    float*  colsum = (float*)(ws + 115769344ull);  // 131,072
    int*    countb = (int*) (ws + 116162560ull);   // 16,384
    int*    offb = (int*)   (ws + 116178944ull);   // 16,384
    int*    curs = (int*)   (ws + 116195328ull);   // 131,072
    int*    eidx = (int*)   (ws + 116326400ull);   // 2,228,224
    float*  eval = (float*) (ws + 118554624ull);   // 2,228,224

    split_all<<<1280, 256, 0, stream>>>(x, W, xh, xm, xl, wth, wtm, wtl,
                                        countb, colsum);
    gemm_xw_mfma<<<dim3(32, 32), 256, 0, stream>>>(xh, xm, xl, wth, wtm, wtl,
                                                   qh, qm, ql, kh, km, kl);
    gemm_qkt_mfma<<<2048, 256, 0, stream>>>(qh, qm, ql, kh, km, kl, attn);
    softmax_topk<<<4096, 256, 0, stream>>>(attn, idx, cnt, countb, nr, colsum);
    scan_offb<<<4, 256, 0, stream>>>(countb, offb, curs);
    fill_csr<<<128, 256, 0, stream>>>(nr, idx, cnt, curs, eidx, eval);
    out_sparse<<<32768, 256, 0, stream>>>(nr, idx, cnt, offb, countb, colsum,
                                          eidx, eval, out);
}

// Round 8
// 481.146 us; speedup vs baseline: 1.0076x; 1.0076x over previous
//
#include <hip/hip_runtime.h>
#include <hip/hip_bf16.h>
#include <math.h>

// Problem constants
#define BB 4
#define NN 1024
#define DD 256
#define CC 8
#define KNBR 16
#define MAXSEL 17   // 16 top-k + possibly the diagonal
#define ZCAP (NN * MAXSEL)   // 17408 max CSR entries per z

typedef __bf16 bf16x8_t __attribute__((ext_vector_type(8)));
typedef float  f32x4_t  __attribute__((ext_vector_type(4)));

// async global->LDS, 16 bytes per lane. LDS base wave-uniform; source address
// is per-lane (gather allowed, keep it coalesced).
__device__ __forceinline__ void gl2lds16(const __bf16* g, __bf16* ldsbase) {
    __builtin_amdgcn_global_load_lds(
        (const __attribute__((address_space(1))) unsigned int*)g,
        (__attribute__((address_space(3))) unsigned int*)ldsbase, 16, 0, 0);
}

// 3-level bf16 split: v = h + m + l + eps, |eps| <= 2^-24 |v|
__device__ __forceinline__ void split3(float v, __bf16& h, __bf16& m, __bf16& l) {
    h = (__bf16)v;
    float r = v - (float)h;
    m = (__bf16)r;
    l = (__bf16)(r - (float)m);
}

// ---------------------------------------------------------------------------
// Kernel 0: fused input prep. Blocks 0..1023: split x. Blocks 1024..1279:
// transpose+split W. Block 1024 zeroes countb; block 1025 zeroes colsum.
// ---------------------------------------------------------------------------
__global__ __launch_bounds__(256) void split_all(const float* __restrict__ x,
                                                 const float* __restrict__ W,
                                                 __bf16* __restrict__ xh,
                                                 __bf16* __restrict__ xm,
                                                 __bf16* __restrict__ xl,
                                                 __bf16* __restrict__ Wth,
                                                 __bf16* __restrict__ Wtm,
                                                 __bf16* __restrict__ Wtl,
                                                 int* __restrict__ countb,
                                                 float* __restrict__ colsum) {
    const int tid = threadIdx.x;
    if (blockIdx.x < 1024) {
        int i = (blockIdx.x * 256 + tid) * 4;
        float4 v = *(const float4*)(x + i);
        __bf16 h0, m0, l0, h1, m1, l1, h2, m2, l2, h3, m3, l3;
        split3(v.x, h0, m0, l0);
        split3(v.y, h1, m1, l1);
        split3(v.z, h2, m2, l2);
        split3(v.w, h3, m3, l3);
        xh[i] = h0; xh[i + 1] = h1; xh[i + 2] = h2; xh[i + 3] = h3;
        xm[i] = m0; xm[i + 1] = m1; xm[i + 2] = m2; xm[i + 3] = m3;
        xl[i] = l0; xl[i + 1] = l1; xl[i + 2] = l2; xl[i + 3] = l3;
    } else {
        const int b2 = blockIdx.x - 1024;
        if (b2 == 0) {
            int4 zz = make_int4(0, 0, 0, 0);
#pragma unroll
            for (int g = 0; g < 4; g++) ((int4*)countb)[tid + 256 * g] = zz;
        }
        if (b2 == 1) {
            float4 zz = make_float4(0.f, 0.f, 0.f, 0.f);
#pragma unroll
            for (int g = 0; g < 32; g++) ((float4*)colsum)[tid + 256 * g] = zz;
        }
        __shared__ float t[64][65];
        const int n0 = (b2 & 63) * 64;
        const int k0 = (b2 >> 6) * 64;
#pragma unroll
        for (int i = 0; i < 16; i++) {
            int k = i * 4 + (tid >> 6);
            int n = tid & 63;
            t[k][n] = W[(size_t)(k0 + k) * 4096 + n0 + n];
        }
        __syncthreads();
#pragma unroll
        for (int i = 0; i < 16; i++) {
            int n = i * 4 + (tid >> 6);
            int k = tid & 63;
            __bf16 h, m, l;
            split3(t[k][n], h, m, l);
            size_t o = (size_t)(n0 + n) * 256 + k0 + k;
            Wth[o] = h; Wtm[o] = m; Wtl[o] = l;
        }
    }
}

// stage one 128x32 bf16 tile. XOR-swizzled: LDS[r][c] = global[r][c ^ s(r)],
// s(r) = (r&3)^((r>>2)&3). Source stays 64B-coalesced.
#define STAGE1(dst, src, rowbase)                                              \
    do {                                                                       \
        gl2lds16(src + (size_t)((rowbase) + r_st) * 256 + k0 + c8s,            \
                 &dst[(w * 64) * 8]);                                          \
        gl2lds16(src + (size_t)((rowbase) + 64 + r_st) * 256 + k0 + c8s,       \
                 &dst[(256 + w * 64) * 8]);                                    \
    } while (0)

// 6-term product ladder, smallest first (hh last)
#define MFMA6(accv, AH, AM, AL, BH, BM, BL)                                    \
    do {                                                                       \
        accv = __builtin_amdgcn_mfma_f32_16x16x32_bf16(AL, BH, accv, 0, 0, 0); \
        accv = __builtin_amdgcn_mfma_f32_16x16x32_bf16(AH, BL, accv, 0, 0, 0); \
        accv = __builtin_amdgcn_mfma_f32_16x16x32_bf16(AM, BM, accv, 0, 0, 0); \
        accv = __builtin_amdgcn_mfma_f32_16x16x32_bf16(AM, BH, accv, 0, 0, 0); \
        accv = __builtin_amdgcn_mfma_f32_16x16x32_bf16(AH, BM, accv, 0, 0, 0); \
        accv = __builtin_amdgcn_mfma_f32_16x16x32_bf16(AH, BH, accv, 0, 0, 0); \
    } while (0)

// ---------------------------------------------------------------------------
// Kernel 1: qk = x @ W via 6-term bf16x3 MFMA; swizzled LDS; LDS-transpose
// epilogue with coalesced bf16x8 stores of the 3-split q/k components.
// ---------------------------------------------------------------------------
__global__ __launch_bounds__(256) void gemm_xw_mfma(
        const __bf16* __restrict__ xh, const __bf16* __restrict__ xm,
        const __bf16* __restrict__ xl, const __bf16* __restrict__ wth,
        const __bf16* __restrict__ wtm, const __bf16* __restrict__ wtl,
        __bf16* __restrict__ qh, __bf16* __restrict__ qm, __bf16* __restrict__ ql,
        __bf16* __restrict__ kh, __bf16* __restrict__ km, __bf16* __restrict__ kl) {
    __shared__ __align__(16) char smem[49152];
    __bf16* Ah = (__bf16*)smem;
    __bf16* Am = Ah + 4096;
    __bf16* Al = Am + 4096;
    __bf16* Bh = Al + 4096;
    __bf16* Bm = Bh + 4096;
    __bf16* Bl = Bm + 4096;
    const int tid = threadIdx.x, lane = tid & 63, w = tid >> 6;
    const int wr = w >> 1, wc = w & 1;
    const int lm = lane & 15, quad = lane >> 4;
    const int row0 = blockIdx.y * 128, col0 = blockIdx.x * 128;
    const int r_st = tid >> 2;
    const int c8s = (((tid & 3) ^ ((tid >> 2) & 3) ^ ((tid >> 4) & 3))) * 8;
    const int rsw = (lm & 3) ^ ((lm >> 2) & 3);
    const int qsw = (quad ^ rsw) * 8;

    f32x4_t acc[4][4];
#pragma unroll
    for (int i = 0; i < 4; i++)
#pragma unroll
        for (int j = 0; j < 4; j++) acc[i][j] = (f32x4_t)(0.f);

    for (int k0 = 0; k0 < 256; k0 += 32) {
        __syncthreads();
        STAGE1(Ah, xh, row0); STAGE1(Am, xm, row0); STAGE1(Al, xl, row0);
        STAGE1(Bh, wth, col0); STAGE1(Bm, wtm, col0); STAGE1(Bl, wtl, col0);
        __syncthreads();

        bf16x8_t ah[4], am[4], al[4];
#pragma unroll
        for (int mi = 0; mi < 4; mi++) {
            int r = (wr * 64 + mi * 16 + lm) * 32 + qsw;
            ah[mi] = *(const bf16x8_t*)&Ah[r];
            am[mi] = *(const bf16x8_t*)&Am[r];
            al[mi] = *(const bf16x8_t*)&Al[r];
        }
#pragma unroll
        for (int ni = 0; ni < 4; ni++) {
            int rb = (wc * 64 + ni * 16 + lm) * 32 + qsw;
            bf16x8_t bh = *(const bf16x8_t*)&Bh[rb];
            bf16x8_t bm = *(const bf16x8_t*)&Bm[rb];
            bf16x8_t bl = *(const bf16x8_t*)&Bl[rb];
#pragma unroll
            for (int mi = 0; mi < 4; mi++)
                MFMA6(acc[mi][ni], ah[mi], am[mi], al[mi], bh, bm, bl);
        }
    }

    // Epilogue: two 64-row passes through LDS (fp32, stride 132 = bank-safe),
    // then coalesced bf16x8 stores of the 3 split components.
    __syncthreads();
    float* tr = (float*)smem;   // 64 x 132 fp32 = 33792 B
    const int s = col0 >> 11, c = (col0 >> 8) & 7, dbase = col0 & 255;
    __bf16* dh = s ? kh : qh;
    __bf16* dm = s ? km : qm;
    __bf16* dl = s ? kl : ql;
    const int rl = tid >> 2;
    const int cb = (tid & 3) * 8;
#pragma unroll
    for (int p = 0; p < 2; p++) {
        if (p) __syncthreads();
        if (wr == p) {
#pragma unroll
            for (int mi = 0; mi < 4; mi++) {
                int rloc = mi * 16 + quad * 4;
#pragma unroll
                for (int ni = 0; ni < 4; ni++) {
                    int cl = wc * 64 + ni * 16 + lm;
#pragma unroll
                    for (int r = 0; r < 4; r++)
                        tr[(rloc + r) * 132 + cl] = acc[mi][ni][r];
                }
            }
        }
        __syncthreads();
        int rr = row0 + p * 64 + rl;
        int bb = rr >> 10, n = rr & 1023;
        size_t base = (((size_t)(bb * CC + c)) * NN + n) * DD + dbase;
#pragma unroll
        for (int g = 0; g < 4; g++) {
            int ccol = g * 32 + cb;
            bf16x8_t hv, mv, lv;
#pragma unroll
            for (int e = 0; e < 8; e++) {
                float vv = tr[rl * 132 + ccol + e];
                __bf16 h, m, l;
                split3(vv, h, m, l);
                hv[e] = h; mv[e] = m; lv[e] = l;
            }
            *(bf16x8_t*)(dh + base + ccol) = hv;
            *(bf16x8_t*)(dm + base + ccol) = mv;
            *(bf16x8_t*)(dl + base + ccol) = lv;
        }
    }
}

// ---------------------------------------------------------------------------
// Kernel 2: per z: attn = (q @ k^T) * scale via 6-term bf16x3 MFMA.
// 1D grid of 2048, swizzled so all 64 blocks of a z share one XCD (id%8);
// XOR-swizzled LDS for conflict-free ds_read_b128.
// ---------------------------------------------------------------------------
__global__ __launch_bounds__(256) void gemm_qkt_mfma(
        const __bf16* __restrict__ qh, const __bf16* __restrict__ qm,
        const __bf16* __restrict__ ql, const __bf16* __restrict__ kh,
        const __bf16* __restrict__ km, const __bf16* __restrict__ kl,
        float* __restrict__ attn) {
    __shared__ __bf16 Ah[128 * 32], Am[128 * 32], Al[128 * 32];
    __shared__ __bf16 Bh[128 * 32], Bm[128 * 32], Bl[128 * 32];
    const int tid = threadIdx.x, lane = tid & 63, w = tid >> 6;
    const int wr = w >> 1, wc = w & 1;
    const int lm = lane & 15, quad = lane >> 4;
    const int id = blockIdx.x;
    const int rb8 = id & 7, qq = id >> 3;
    const int j = qq & 63, zhi = qq >> 6;
    const int z = zhi * 8 + rb8;
    const int row0 = (j >> 3) * 128, col0 = (j & 7) * 128;
    const size_t zo = (size_t)z * NN * DD;
    float* Cm = attn + (size_t)z * NN * NN;
    const int r_st = tid >> 2;
    const int c8s = (((tid & 3) ^ ((tid >> 2) & 3) ^ ((tid >> 4) & 3))) * 8;
    const int rsw = (lm & 3) ^ ((lm >> 2) & 3);
    const int qsw = (quad ^ rsw) * 8;
    const float scale = 0.0625f;

    f32x4_t acc[4][4];
#pragma unroll
    for (int i = 0; i < 4; i++)
#pragma unroll
        for (int j2 = 0; j2 < 4; j2++) acc[i][j2] = (f32x4_t)(0.f);

    for (int k0 = 0; k0 < 256; k0 += 32) {
        __syncthreads();
        STAGE1(Ah, (qh + zo), row0); STAGE1(Am, (qm + zo), row0); STAGE1(Al, (ql + zo), row0);
        STAGE1(Bh, (kh + zo), col0); STAGE1(Bm, (km + zo), col0); STAGE1(Bl, (kl + zo), col0);
        __syncthreads();

        bf16x8_t ah[4], am[4], al[4];
#pragma unroll
        for (int mi = 0; mi < 4; mi++) {
            int r = (wr * 64 + mi * 16 + lm) * 32 + qsw;
            ah[mi] = *(const bf16x8_t*)&Ah[r];
            am[mi] = *(const bf16x8_t*)&Am[r];
            al[mi] = *(const bf16x8_t*)&Al[r];
        }
#pragma unroll
        for (int ni = 0; ni < 4; ni++) {
            int rbb = (wc * 64 + ni * 16 + lm) * 32 + qsw;
            bf16x8_t bh = *(const bf16x8_t*)&Bh[rbb];
            bf16x8_t bm = *(const bf16x8_t*)&Bm[rbb];
            bf16x8_t bl = *(const bf16x8_t*)&Bl[rbb];
#pragma unroll
            for (int mi = 0; mi < 4; mi++)
                MFMA6(acc[mi][ni], ah[mi], am[mi], al[mi], bh, bm, bl);
        }
    }

#pragma unroll
    for (int mi = 0; mi < 4; mi++)
#pragma unroll
        for (int ni = 0; ni < 4; ni++) {
            int row = row0 + wr * 64 + mi * 16 + quad * 4;
            int col = col0 + wc * 64 + ni * 16 + lm;
#pragma unroll
            for (int r = 0; r < 4; r++)
                Cm[(size_t)(row + r) * NN + col] = acc[mi][ni][r] * scale;
        }
}

// ---------------------------------------------------------------------------
// Kernel 3: per (b,n): softmax for all 8 channels (wave w owns channels
// 2w,2w+1; probs stashed in LDS), column channel-sum, wave-parallel top-16
// (scratch-free predicated eviction), ALL-wave redundant 64-candidate merge
// (disjoint ranges -> identical deterministic result per wave), fused rownorm.
// ---------------------------------------------------------------------------
__global__ __launch_bounds__(256) void softmax_topk(const float* __restrict__ attn,
                                                    int* __restrict__ idx,
                                                    int* __restrict__ cnt,
                                                    int* __restrict__ countb,
                                                    float* __restrict__ nr,
                                                    float* __restrict__ colsum) {
    __shared__ float prob[CC][NN];   // 32 KB
    __shared__ float cval[64];
    __shared__ int cidx[64];
    const int bn = blockIdx.x, b = bn >> 10, n = bn & 1023;
    const int tid = threadIdx.x, lane = tid & 63, w = tid >> 6;

    // 1) per-wave softmax of channels 2w, 2w+1; stash probs
#pragma unroll
    for (int cc = 0; cc < 2; cc++) {
        const int c = w * 2 + cc;
        const float* src = attn + ((size_t)(b * CC + c) * NN + n) * NN;
        float4 v[4];
#pragma unroll
        for (int g = 0; g < 4; g++) v[g] = *(const float4*)(src + g * 256 + lane * 4);
        float mx = -INFINITY;
#pragma unroll
        for (int g = 0; g < 4; g++)
            mx = fmaxf(mx, fmaxf(fmaxf(v[g].x, v[g].y), fmaxf(v[g].z, v[g].w)));
#pragma unroll
        for (int off = 32; off; off >>= 1) mx = fmaxf(mx, __shfl_xor(mx, off));
        float sm = 0.f;
#pragma unroll
        for (int g = 0; g < 4; g++) {
            v[g].x = expf(v[g].x - mx); v[g].y = expf(v[g].y - mx);
            v[g].z = expf(v[g].z - mx); v[g].w = expf(v[g].w - mx);
            sm += v[g].x + v[g].y + v[g].z + v[g].w;
        }
#pragma unroll
        for (int off = 32; off; off >>= 1) sm += __shfl_xor(sm, off);
        const float inv = 1.0f / sm;
#pragma unroll
        for (int g = 0; g < 4; g++) {
            v[g].x *= inv; v[g].y *= inv; v[g].z *= inv; v[g].w *= inv;
            *(float4*)&prob[c][g * 256 + lane * 4] = v[g];
        }
    }
    __syncthreads();

    // 2) channel-sum for this thread's 4 columns (cols tid*4..tid*4+3)
    float va0, va1, va2, va3;
    {
        float4 a4 = make_float4(0.f, 0.f, 0.f, 0.f);
#pragma unroll
        for (int c = 0; c < CC; c++) {
            float4 p = *(const float4*)&prob[c][tid * 4];
            a4.x += p.x; a4.y += p.y; a4.z += p.z; a4.w += p.w;
        }
        va0 = a4.x; va1 = a4.y; va2 = a4.z; va3 = a4.w;
    }

    // 3) per-wave top-16 over cols [w*256, w*256+256), register-resident,
    //    scratch-free predicated eviction
    float keepv = -INFINITY; int keepi = 0;
    for (int it = 0; it < KNBR; it++) {
        float bv = va0; int bj = 0;
        if (va1 > bv) { bv = va1; bj = 1; }
        if (va2 > bv) { bv = va2; bj = 2; }
        if (va3 > bv) { bv = va3; bj = 3; }
        int bi = tid * 4 + bj;
#pragma unroll
        for (int off = 1; off < 64; off <<= 1) {
            float ov = __shfl_xor(bv, off);
            int oi = __shfl_xor(bi, off);
            if (ov > bv || (ov == bv && oi < bi)) { bv = ov; bi = oi; }
        }
        if (lane == it) { keepv = bv; keepi = bi; }
        const bool mine = (bi >> 2) == tid;
        const int sj = bi & 3;
        va0 = (mine && sj == 0) ? -INFINITY : va0;
        va1 = (mine && sj == 1) ? -INFINITY : va1;
        va2 = (mine && sj == 2) ? -INFINITY : va2;
        va3 = (mine && sj == 3) ? -INFINITY : va3;
    }
    if (lane < KNBR) { cval[w * KNBR + lane] = keepv; cidx[w * KNBR + lane] = keepi; }
    __syncthreads();

    // 4) all waves merge the 64 candidates redundantly (disjoint column
    //    ranges -> candidates globally unique -> deterministic identical
    //    result). Lane it ends holding global selection #it in gsel.
    float curv = cval[lane]; int curi = cidx[lane];
    int gsel = -1;
    for (int it = 0; it < KNBR; it++) {
        float bv = curv; int bi = curi;
#pragma unroll
        for (int off = 1; off < 64; off <<= 1) {
            float ov = __shfl_xor(bv, off);
            int oi = __shfl_xor(bi, off);
            if (ov > bv || (ov == bv && oi < bi)) { bv = ov; bi = oi; }
        }
        if (lane == it) gsel = bi;
        if (curi == bi) curv = -INFINITY;
    }
    // diagonal insertion, per-wave (no barrier needed)
    const bool has = __ballot(lane < KNBR && gsel == n) != 0ull;
    const int c_ = has ? KNBR : (KNBR + 1);
    if (!has && lane == KNBR) gsel = n;
    const int gi = (lane < c_) ? gsel : 0;

    // wave 0 writes selection metadata
    if (w == 0) {
        if (lane < c_) {
            idx[bn * MAXSEL + lane] = gi;
            atomicAdd(&countb[b * NN + gi], 1);
        }
        if (lane == 0) cnt[bn] = c_;
    }

    // 5) fused rownorm: wave w normalizes its 2 channels' selected probs
#pragma unroll
    for (int cc = 0; cc < 2; cc++) {
        const int c = w * 2 + cc;
        const int z = b * CC + c;
        const int t = z * NN + n;
        float p = (lane < c_) ? prob[c][gi] : 0.f;
        float s = p;
#pragma unroll
        for (int off = 1; off < 64; off <<= 1) s += __shfl_xor(s, off);
        float v = p / (s + 1e-6f);
        if (lane < c_) {
            nr[(size_t)t * MAXSEL + lane] = v;
            atomicAdd(&colsum[(size_t)z * NN + gi], v);
        }
    }
}

// ---------------------------------------------------------------------------
// Kernel 4: per b: exclusive prefix scan of countb -> offb; init curs.
// ---------------------------------------------------------------------------
__global__ __launch_bounds__(256) void scan_offb(const int* __restrict__ countb,
                                                 int* __restrict__ offb,
                                                 int* __restrict__ curs) {
    __shared__ int wtot[4];
    const int b = blockIdx.x, tid = threadIdx.x, lane = tid & 63, w = tid >> 6;
    int c0 = countb[b * NN + tid * 4 + 0];
    int c1 = countb[b * NN + tid * 4 + 1];
    int c2 = countb[b * NN + tid * 4 + 2];
    int c3 = countb[b * NN + tid * 4 + 3];
    int tsum = c0 + c1 + c2 + c3;
    int incl = tsum;
#pragma unroll
    for (int off = 1; off < 64; off <<= 1) {
        int v = __shfl_up(incl, off);
        if (lane >= off) incl += v;
    }
    if (lane == 63) wtot[w] = incl;
    __syncthreads();
    int woff = 0;
    for (int i = 0; i < w; i++) woff += wtot[i];
    int base = woff + incl - tsum;
    int o0 = base, o1 = base + c0, o2 = base + c0 + c1, o3 = base + c0 + c1 + c2;
    offb[b * NN + tid * 4 + 0] = o0;
    offb[b * NN + tid * 4 + 1] = o1;
    offb[b * NN + tid * 4 + 2] = o2;
    offb[b * NN + tid * 4 + 3] = o3;
#pragma unroll
    for (int c = 0; c < CC; c++) {
        int z = b * CC + c;
        curs[z * NN + tid * 4 + 0] = o0;
        curs[z * NN + tid * 4 + 1] = o1;
        curs[z * NN + tid * 4 + 2] = o2;
        curs[z * NN + tid * 4 + 3] = o3;
    }
}

// ---------------------------------------------------------------------------
// Kernel 5: fill CSR entries from nr/idx (tiny: 2.5 MB traffic).
// ---------------------------------------------------------------------------
__global__ __launch_bounds__(256) void fill_csr(const float* __restrict__ nr,
                                                const int* __restrict__ idx,
                                                const int* __restrict__ cnt,
                                                int* __restrict__ curs,
                                                int* __restrict__ eidx,
                                                float* __restrict__ eval) {
    const int t = blockIdx.x * 256 + threadIdx.x;  // z*N + n
    const int z = t >> 10, n = t & 1023;
    const int b = z >> 3;
    const int bn = b * NN + n;
    const int c_ = cnt[bn];
    const size_t zb = (size_t)z * ZCAP;
#pragma unroll
    for (int j = 0; j < MAXSEL; j++) {
        if (j < c_) {
            int k = idx[bn * MAXSEL + j];
            float v = nr[(size_t)t * MAXSEL + j];
            int p = atomicAdd(&curs[z * NN + k], 1);
            eidx[zb + p] = n;
            eval[zb + p] = v;
        }
    }
}

// ---------------------------------------------------------------------------
// Kernel 6: out[z][n][:] = sum_j w_j/(colsum_j+eps) * sparse_col(k_j).
// Block per (z,n). 17 groups of 15 threads, contiguous CSR slices.
// ---------------------------------------------------------------------------
__global__ __launch_bounds__(256) void out_sparse(const float* __restrict__ nr,
                                                  const int* __restrict__ idx,
                                                  const int* __restrict__ cnt,
                                                  const int* __restrict__ offb,
                                                  const int* __restrict__ countb,
                                                  const float* __restrict__ colsum,
                                                  const int* __restrict__ eidx,
                                                  const float* __restrict__ eval,
                                                  float* __restrict__ out) {
    __shared__ float row[NN];
    __shared__ float gscale[MAXSEL];
    __shared__ int goff[MAXSEL];
    __shared__ int glen[MAXSEL];
    const int t = blockIdx.x;  // z*N + n
    const int z = t >> 10;
    const int b = z >> 3;
    const int bn = b * NN + (t & 1023);
    const int tid = threadIdx.x;
    const size_t zb = (size_t)z * ZCAP;

    ((float4*)row)[tid] = make_float4(0.f, 0.f, 0.f, 0.f);
    const int c_ = cnt[bn];
    if (tid < MAXSEL) {
        float sc = 0.f;
        int off = 0, len = 0;
        if (tid < c_) {
            int k = idx[bn * MAXSEL + tid];
            float wgt = nr[(size_t)t * MAXSEL + tid];
            sc = wgt / (colsum[(size_t)z * NN + k] + 1e-6f);
            off = offb[b * NN + k];
            len = countb[b * NN + k];
        }
        gscale[tid] = sc; goff[tid] = off; glen[tid] = len;
    }
    __syncthreads();
    const int j = tid / 15;       // 17 groups of 15 (tid 255 idle)
    const int lg = tid - j * 15;
    if (j < MAXSEL) {
        const float sc = gscale[j];
        const int off = goff[j], len = glen[j];
        for (int i = lg; i < len; i += 15) {
            int m = eidx[zb + off + i];
            float v = eval[zb + off + i];
            atomicAdd(&row[m], sc * v);
        }
    }
    __syncthreads();
    *(float4*)(out + (size_t)t * NN + tid * 4) = ((float4*)row)[tid];
}

// ---------------------------------------------------------------------------
extern "C" void kernel_launch(void* const* d_in, const int* in_sizes, int n_in,
                              void* d_out, int out_size, void* d_ws, size_t ws_size,
                              hipStream_t stream) {
    const float* x = (const float*)d_in[0];    // [4,1024,256]
    const float* W = (const float*)d_in[1];    // [256,4096]
    float* out = (float*)d_out;                // [4,8,1024,1024]
    char* ws = (char*)d_ws;

    // attn (raw logits*scale) lives in d_out; dead before out_sparse writes.
    float* attn = (float*)d_out;

    // workspace layout (bytes)
    __bf16* qh   = (__bf16*)(ws);
    __bf16* qm   = (__bf16*)(ws + 16777216ull);
    __bf16* ql   = (__bf16*)(ws + 33554432ull);
    __bf16* kh   = (__bf16*)(ws + 50331648ull);
    __bf16* km   = (__bf16*)(ws + 67108864ull);
    __bf16* kl   = (__bf16*)(ws + 83886080ull);
    __bf16* xh   = (__bf16*)(ws + 100663296ull);
    __bf16* xm   = (__bf16*)(ws + 102760448ull);
    __bf16* xl   = (__bf16*)(ws + 104857600ull);
    __bf16* wth  = (__bf16*)(ws + 106954752ull);
    __bf16* wtm  = (__bf16*)(ws + 109051904ull);
    __bf16* wtl  = (__bf16*)(ws + 111149056ull);
    int*    idx  = (int*)   (ws + 113246208ull);   // 278,528
    int*    cnt  = (int*)   (ws + 113524736ull);   // 16,384
    float*  nr   = (float*) (ws + 113541120ull);   // 2,228,224
    float*  colsum = (float*)(ws + 115769344ull);  // 131,072
    int*    countb = (int*) (ws + 116162560ull);   // 16,384
    int*    offb = (int*)   (ws + 116178944ull);   // 16,384
    int*    curs = (int*)   (ws + 116195328ull);   // 131,072
    int*    eidx = (int*)   (ws + 116326400ull);   // 2,228,224
    float*  eval = (float*) (ws + 118554624ull);   // 2,228,224

    split_all<<<1280, 256, 0, stream>>>(x, W, xh, xm, xl, wth, wtm, wtl,
                                        countb, colsum);
    gemm_xw_mfma<<<dim3(32, 32), 256, 0, stream>>>(xh, xm, xl, wth, wtm, wtl,
                                                   qh, qm, ql, kh, km, kl);
    gemm_qkt_mfma<<<2048, 256, 0, stream>>>(qh, qm, ql, kh, km, kl, attn);
    softmax_topk<<<4096, 256, 0, stream>>>(attn, idx, cnt, countb, nr, colsum);
    scan_offb<<<4, 256, 0, stream>>>(countb, offb, curs);
    fill_csr<<<128, 256, 0, stream>>>(nr, idx, cnt, curs, eidx, eval);
    out_sparse<<<32768, 256, 0, stream>>>(nr, idx, cnt, offb, countb, colsum,
                                          eidx, eval, out);
}